// Round 14
// baseline (5953.262 us; speedup 1.0000x reference)
//
#include <hip/hip_runtime.h>
#include <hip/hip_bf16.h>

#define B_  64
#define T_  12
#define N_  325
#define DIN 2
#define H_  128
#define BN  (B_*N_)    // 20800
#define DPITCH 384     // padded node pitch (k-extent)
#define AROWS 384      // padded m-rows per support matrix

typedef __hip_bfloat16 bf16;
typedef unsigned short u16;
typedef __attribute__((ext_vector_type(8))) short short8;
typedef __attribute__((ext_vector_type(4))) float f32x4;

__device__ __forceinline__ float b2f(bf16 v){ return __bfloat162float(v); }
__device__ __forceinline__ u16 f2b(float f){
    __hip_bfloat16 h = __float2bfloat16(f);
    return *reinterpret_cast<u16*>(&h);
}
__device__ __forceinline__ float ldf(const void* p, size_t i, int bf){
    return bf ? b2f(((const bf16*)p)[i]) : ((const float*)p)[i];
}

// async global->LDS, 16B per lane; dest = base + lane*16 (wave-uniform base)
__device__ __forceinline__ void gl_lds16(const u16* g, u16* l){
    __builtin_amdgcn_global_load_lds(
        (const __attribute__((address_space(1))) unsigned int*)g,
        (__attribute__((address_space(3))) unsigned int*)l, 16, 0, 0);
}

// ---------------------------------------------------------------------------
struct FillCfg { u16 *F, *Ft; const float *x, *h; long xbs;
                 int C, KC, Cpad, xoff, xdim, hoff, ftiles, b0, nb; };
struct DiffCfg { u16* F; const u16* Ft; int C, KC, Cpad, coff, ctiles, T, nb; };
struct GemmCfg { const u16* Fb; const u16* Wt; const float* bias; float* zr; float* hb;
                 int KC, KCpad, rows, gy, ct, nb; };
struct RhCfg  { u16 *F, *Ft; const float *zr, *h; int KC, Cpad, hoff, b0, total, nb; };

// ---------------------------------------------------------------------------
__global__ void sniff(const void* __restrict__ sup, int* __restrict__ flag){
    if (threadIdx.x == 0 && blockIdx.x == 0){
        float sb = 0.f, sf = 0.f;
        for (int n = 0; n < N_; ++n){
            sb += b2f(((const bf16*)sup)[n]);
            sf += ((const float*)sup)[n];
        }
        float db = fabsf(sb - 1.f), df = fabsf(sf - 1.f);
        *flag = (db < df) ? 1 : 0;
    }
}

struct CvtArgs { const void* src[12]; float* dst[12]; int n[12]; };

__global__ void cvt_all(CvtArgs a, const int* __restrict__ flag){
    int ii = blockIdx.y;
    int i  = blockIdx.x*256 + threadIdx.x;
    if (i >= a.n[ii]) return;
    a.dst[ii][i] = ldf(a.src[ii], i, *flag);
}

// ---------------------------------------------------------------------------
__global__ void support_prep(const void* __restrict__ sup, const int* __restrict__ flag,
                             float* __restrict__ msq){
    int bf = *flag;
    int s = blockIdx.z;
    int m = blockIdx.y*16 + threadIdx.y;
    int n = blockIdx.x*16 + threadIdx.x;
    __shared__ float As[16][17], Bs[16][17];
    size_t base = (size_t)s*N_*N_;
    float acc = 0.f;
    for (int j0 = 0; j0 < N_; j0 += 16){
        As[threadIdx.y][threadIdx.x] = (m < N_ && j0+threadIdx.x < N_) ? ldf(sup, base + (size_t)m*N_ + j0+threadIdx.x, bf) : 0.f;
        Bs[threadIdx.y][threadIdx.x] = (j0+threadIdx.y < N_ && n < N_) ? ldf(sup, base + (size_t)(j0+threadIdx.y)*N_ + n, bf) : 0.f;
        __syncthreads();
        #pragma unroll
        for (int jj=0; jj<16; ++jj) acc += As[threadIdx.y][jj]*Bs[jj][threadIdx.x];
        __syncthreads();
    }
    if (m < N_ && n < N_){
        msq[(size_t)(2*s  )*N_*N_ + m*N_ + n] = ldf(sup, base + (size_t)m*N_ + n, bf);
        msq[(size_t)(2*s+1)*N_*N_ + m*N_ + n] = acc;
    }
}

__global__ void asq_prep(const float* __restrict__ msq, u16* __restrict__ asq){
    int idx = blockIdx.x*256 + threadIdx.x;
    int total = 4*AROWS*DPITCH;
    if (idx >= total) return;
    int col = idx % DPITCH;
    int rm  = idx / DPITCH;
    int m   = rm % AROWS;
    int k   = rm / AROWS;
    asq[idx] = (m < N_ && col < N_) ? f2b(msq[((size_t)k*N_ + m)*N_ + col]) : 0;
}

// ---------------------------------------------------------------------------
// Weight transpose with optional L0 row permutation ([x|h] -> [h|x] feature
// order): permC>0 => orig_local = (kl<128)? kl+2 : kl-128 within each slot.
// ---------------------------------------------------------------------------
__global__ __launch_bounds__(256) void wtrans(const void* __restrict__ W, u16* __restrict__ Wt,
                                              int KC, int Nout, int KCpad, int permC,
                                              const int* __restrict__ flag){
    int bf = *flag;
    int k0 = blockIdx.x*64, c0 = blockIdx.y*64;
    int tid = threadIdx.x;
    __shared__ u16 T[64][72];
    #pragma unroll
    for (int it=0; it<2; ++it){
        int lin = it*256 + tid;
        int kl = lin >> 3, seg = lin & 7;
        int gk = k0 + kl, gc = c0 + seg*8;
        u16 tmp[8];
        int ok = (gk < KC);
        size_t orow = 0;
        if (ok){
            int r = gk;
            if (permC > 0){
                int s  = gk / permC;
                int lo = gk % permC;
                r = s*permC + ((lo < 128) ? lo + 2 : lo - 128);
            }
            orow = (size_t)r * Nout;
        }
        #pragma unroll
        for (int e=0;e<8;++e) tmp[e] = ok ? f2b(ldf(W, orow + gc + e, bf)) : 0;
        *(uint4*)&T[kl][seg*8] = *(const uint4*)tmp;
    }
    __syncthreads();
    #pragma unroll
    for (int it=0; it<2; ++it){
        int lin = it*256 + tid;
        int cl = lin >> 3, seg = lin & 7;
        u16 tmp[8];
        #pragma unroll
        for (int j=0;j<8;++j) tmp[j] = T[seg*8+j][cl];
        *(uint4*)(Wt + (size_t)(c0+cl)*KCpad + k0 + seg*8) = *(const uint4*)tmp;
    }
}

// ---------------------------------------------------------------------------
// fill_k: F slot0 + Ft transpose; generalized column mapping (xoff/xdim/hoff)
// and partial fill (ftiles c-tiles). Dual-cfg merged grid.
// ---------------------------------------------------------------------------
__global__ __launch_bounds__(256) void fill_k(FillCfg ca, FillCfg cb, int na){
    int bi = blockIdx.x;
    FillCfg c = ca;
    if (bi >= na){ c = cb; bi -= na; }
    int nblk = bi % 6;
    int rest = bi / 6;
    int cblk = rest % c.ftiles;
    int bl   = rest / c.ftiles;
    int bg = c.b0 + bl;
    int n0 = nblk*64, c0 = cblk*64;
    int tid = threadIdx.x;
    __shared__ u16 T[64][72];
    #pragma unroll
    for (int it=0; it<2; ++it){
        int lin = it*256 + tid;
        int nl = lin >> 3, seg = lin & 7;
        int gn = n0 + nl;
        u16 tmp[8];
        #pragma unroll
        for (int e=0;e<8;++e){
            int cc = c0 + seg*8 + e;
            float v = 0.f;
            if (gn < N_){
                if (cc >= c.xoff && cc < c.xoff + c.xdim)
                    v = c.x[(size_t)bg*c.xbs + (size_t)gn*c.xdim + (cc - c.xoff)];
                else if (cc >= c.hoff && cc < c.hoff + 128)
                    v = c.h[((size_t)bg*N_ + gn)*H_ + (cc - c.hoff)];
            }
            tmp[e] = f2b(v);
        }
        *(uint4*)&T[nl][seg*8] = *(const uint4*)tmp;
        if (gn < N_){
            int cbase = c0 + seg*8;
            u16* dst = c.F + ((size_t)bl*N_ + gn)*c.KC + cbase;
            if (cbase + 7 < c.C){
                *(uint4*)dst = *(const uint4*)tmp;
            } else {
                #pragma unroll
                for (int e=0;e<8;++e) if (cbase + e < c.C) dst[e] = tmp[e];
            }
        }
    }
    __syncthreads();
    #pragma unroll
    for (int it=0; it<2; ++it){
        int lin = it*256 + tid;
        int cl = lin >> 3, seg = lin & 7;
        u16 tmp[8];
        #pragma unroll
        for (int j=0;j<8;++j) tmp[j] = T[seg*8+j][cl];
        *(uint4*)(c.Ft + (size_t)bl*c.Cpad*DPITCH + (size_t)(c0+cl)*DPITCH + n0 + seg*8)
            = *(const uint4*)tmp;
    }
}

// ---------------------------------------------------------------------------
__global__ void rh_k(RhCfg ca, RhCfg cb, int na){
    int blk = blockIdx.x;
    RhCfg c = ca;
    if (blk >= na){ c = cb; blk -= na; }
    int idx = blk*256 + threadIdx.x;
    if (idx >= c.total) return;
    int j   = idx & 127;
    int bnl = idx >> 7;
    int bl  = bnl / N_;
    int n   = bnl % N_;
    float r  = c.zr[(size_t)bnl*256 + 128 + j];
    float hv = c.h[((size_t)c.b0*N_ + bnl)*128 + j];
    u16 v = f2b(r * hv);
    c.F[(size_t)bnl*c.KC + c.hoff + j] = v;
    c.Ft[((size_t)bl*c.Cpad + c.hoff + j)*DPITCH + n] = v;
}

// ---------------------------------------------------------------------------
// diffuse_k: hot loop (128m x 64c, async staging + swizzle, XCD-pinned).
// ---------------------------------------------------------------------------
__global__ __launch_bounds__(256) void diffuse_k(DiffCfg ca, DiffCfg cb, int na,
                                                 const u16* __restrict__ asq){
    int bi = blockIdx.x;
    DiffCfg c = ca;
    if (bi >= na){ c = cb; bi -= na; }
    int xcd = bi & 7, m8 = bi >> 3;
    int tg = m8 / 12, s = m8 % 12;
    int t = tg*8 + xcd;
    if (t >= c.T) return;
    int bl = t / c.ctiles, cbk = t % c.ctiles;
    int y = s % 3, k = s / 3;

    const u16* A    = asq + (size_t)k*AROWS*DPITCH;
    const u16* Bt_g = c.Ft + ((size_t)bl*c.Cpad + c.coff)*DPITCH;
    u16*       Cm   = c.F + (size_t)bl*N_*c.KC + (size_t)(k+1)*c.C + c.coff;

    int m0 = y * 128;
    int c0 = cbk * 64;
    int tid = threadIdx.x;
    int wv = tid >> 6, lane = tid & 63, l15 = lane & 15, quad = lane >> 4;
    int lr = lane >> 3, ls = lane & 7;

    __shared__ u16 As[128*64];
    __shared__ u16 Bs[64*64];

    f32x4 acc[2][4];
    #pragma unroll
    for (int i2=0;i2<2;++i2)
        #pragma unroll
        for (int j=0;j<4;++j) acc[i2][j] = (f32x4){0.f,0.f,0.f,0.f};

    for (int k0 = 0; k0 < N_; k0 += 64){
        #pragma unroll
        for (int j=0;j<4;++j){
            int row = wv*32 + j*8 + lr;
            int seg = ls ^ lr;
            gl_lds16(A + (size_t)(m0+row)*DPITCH + k0 + seg*8, &As[(wv*32 + j*8)*64]);
        }
        #pragma unroll
        for (int j=0;j<2;++j){
            int row = wv*16 + j*8 + lr;
            int seg = ls ^ lr;
            gl_lds16(Bt_g + (size_t)(c0+row)*DPITCH + k0 + seg*8, &Bs[(wv*16 + j*8)*64]);
        }
        __syncthreads();
        #pragma unroll
        for (int ks = 0; ks < 64; ks += 32){
            int sw = (((ks>>3) + quad) ^ (l15 & 7)) << 3;
            short8 a0 = *(const short8*)&As[(wv*32      + l15)*64 + sw];
            short8 a1 = *(const short8*)&As[(wv*32 + 16 + l15)*64 + sw];
            short8 b0 = *(const short8*)&Bs[(     l15)*64 + sw];
            short8 b1 = *(const short8*)&Bs[(16 + l15)*64 + sw];
            short8 b2 = *(const short8*)&Bs[(32 + l15)*64 + sw];
            short8 b3 = *(const short8*)&Bs[(48 + l15)*64 + sw];
            acc[0][0] = __builtin_amdgcn_mfma_f32_16x16x32_bf16(a0,b0,acc[0][0],0,0,0);
            acc[0][1] = __builtin_amdgcn_mfma_f32_16x16x32_bf16(a0,b1,acc[0][1],0,0,0);
            acc[0][2] = __builtin_amdgcn_mfma_f32_16x16x32_bf16(a0,b2,acc[0][2],0,0,0);
            acc[0][3] = __builtin_amdgcn_mfma_f32_16x16x32_bf16(a0,b3,acc[0][3],0,0,0);
            acc[1][0] = __builtin_amdgcn_mfma_f32_16x16x32_bf16(a1,b0,acc[1][0],0,0,0);
            acc[1][1] = __builtin_amdgcn_mfma_f32_16x16x32_bf16(a1,b1,acc[1][1],0,0,0);
            acc[1][2] = __builtin_amdgcn_mfma_f32_16x16x32_bf16(a1,b2,acc[1][2],0,0,0);
            acc[1][3] = __builtin_amdgcn_mfma_f32_16x16x32_bf16(a1,b3,acc[1][3],0,0,0);
        }
        __syncthreads();
    }
    #pragma unroll
    for (int i2=0;i2<2;++i2){
        #pragma unroll
        for (int j=0;j<4;++j){
            int cc = c0 + j*16 + l15;
            #pragma unroll
            for (int r=0;r<4;++r){
                int m = m0 + wv*32 + i2*16 + quad*4 + r;
                if (m < N_ && c.coff + cc < c.C) Cm[(size_t)m*c.KC + cc] = f2b(acc[i2][j][r]);
            }
        }
    }
}

// ---------------------------------------------------------------------------
// diffx_k: diffusion of the L0 x-columns (2 real cols at coff=128), B-operand
// synthesized in-kernel from fp32 xdec. One c-tile; only j=0 frag computed.
// ---------------------------------------------------------------------------
__global__ __launch_bounds__(256) void diffx_k(u16* __restrict__ F,
                                               const float* __restrict__ xdec,
                                               const u16* __restrict__ asq,
                                               int C, int KC, int coff){
    int bi = blockIdx.x;
    int xcd = bi & 7, m8 = bi >> 3;
    int tg = m8 / 12, s = m8 % 12;
    int t = tg*8 + xcd;
    if (t >= B_) return;
    int bl = t;
    int y = s % 3, k = s / 3;

    const u16* A  = asq + (size_t)k*AROWS*DPITCH;
    u16*       Cm = F + (size_t)bl*N_*KC + (size_t)(k+1)*C + coff;

    int m0 = y * 128;
    int tid = threadIdx.x;
    int wv = tid >> 6, lane = tid & 63, l15 = lane & 15, quad = lane >> 4;
    int lr = lane >> 3, ls = lane & 7;

    __shared__ u16 As[128*64];
    __shared__ u16 Bs[64*64];

    f32x4 acc0 = (f32x4){0.f,0.f,0.f,0.f};
    f32x4 acc1 = (f32x4){0.f,0.f,0.f,0.f};

    for (int k0 = 0; k0 < N_; k0 += 64){
        #pragma unroll
        for (int j=0;j<4;++j){
            int row = wv*32 + j*8 + lr;
            int seg = ls ^ lr;
            gl_lds16(A + (size_t)(m0+row)*DPITCH + k0 + seg*8, &As[(wv*32 + j*8)*64]);
        }
        // synthesize B tile: rows 0,1 = bf16(xdec), rest 0 (swizzled layout)
        #pragma unroll
        for (int i=0;i<16;++i){
            int lin = tid*16 + i;
            int row = lin >> 6;
            int kk  = lin & 63;
            u16 v = 0;
            if (row < 2 && k0 + kk < N_)
                v = f2b(xdec[((size_t)bl*N_ + k0 + kk)*2 + row]);
            int seg = kk >> 3, e = kk & 7;
            Bs[row*64 + ((seg ^ (row&7))<<3) + e] = v;
        }
        __syncthreads();
        #pragma unroll
        for (int ks = 0; ks < 64; ks += 32){
            int sw = (((ks>>3) + quad) ^ (l15 & 7)) << 3;
            short8 a0 = *(const short8*)&As[(wv*32      + l15)*64 + sw];
            short8 a1 = *(const short8*)&As[(wv*32 + 16 + l15)*64 + sw];
            short8 b0 = *(const short8*)&Bs[(     l15)*64 + sw];
            acc0 = __builtin_amdgcn_mfma_f32_16x16x32_bf16(a0,b0,acc0,0,0,0);
            acc1 = __builtin_amdgcn_mfma_f32_16x16x32_bf16(a1,b0,acc1,0,0,0);
        }
        __syncthreads();
    }
    if (l15 < 2){
        #pragma unroll
        for (int i2=0;i2<2;++i2){
            f32x4 a = i2 ? acc1 : acc0;
            #pragma unroll
            for (int r=0;r<4;++r){
                int m = m0 + wv*32 + i2*16 + quad*4 + r;
                if (m < N_) Cm[(size_t)m*KC + l15] = f2b(a[r]);
            }
        }
    }
}

// ---------------------------------------------------------------------------
// gemm_k: hot loop (128m x 64c, async staging + swizzle, XCD-pinned).
// MODE 0: zr = sigmoid. MODE 1: GRU update.
// ---------------------------------------------------------------------------
template<int MODE>
__global__ __launch_bounds__(256) void gemm_k(GemmCfg ca, GemmCfg cb, int na){
    int bi = blockIdx.x;
    GemmCfg c = ca;
    if (bi >= na){ c = cb; bi -= na; }
    int xcd = bi & 7, q = bi >> 3;
    int cbk = q % c.ct;
    int rt  = (q / c.ct)*8 + xcd;
    if (rt >= c.gy) return;
    int r0 = rt * 128;
    int c0 = cbk * 64;
    int tid = threadIdx.x;
    int wv = tid >> 6, lane = tid & 63, l15 = lane & 15, quad = lane >> 4;
    int lr = lane >> 3, ls = lane & 7;

    __shared__ u16 As[128*64];
    __shared__ u16 Bs[64*64];

    f32x4 acc[2][4];
    #pragma unroll
    for (int i2=0;i2<2;++i2)
        #pragma unroll
        for (int j=0;j<4;++j) acc[i2][j] = (f32x4){0.f,0.f,0.f,0.f};

    for (int k0 = 0; k0 < c.KCpad; k0 += 64){
        if (k0 + 64 <= c.KC){
            #pragma unroll
            for (int j=0;j<4;++j){
                int row = wv*32 + j*8 + lr;
                int seg = ls ^ lr;
                gl_lds16(c.Fb + (size_t)(r0+row)*c.KC + k0 + seg*8, &As[(wv*32 + j*8)*64]);
            }
        } else {
            #pragma unroll
            for (int it=0; it<4; ++it){
                int lin = it*256 + tid;
                int row = lin >> 3, sp = lin & 7;
                int seg = sp ^ (row & 7);
                int gr = r0 + row, gk = k0 + seg*8;
                u16 tmp[8];
                #pragma unroll
                for (int e=0;e<8;++e)
                    tmp[e] = (gk+e < c.KC) ? c.Fb[(size_t)gr*c.KC + gk+e] : (u16)0;
                *(uint4*)&As[row*64 + sp*8] = *(const uint4*)tmp;
            }
        }
        #pragma unroll
        for (int j=0;j<2;++j){
            int row = wv*16 + j*8 + lr;
            int seg = ls ^ lr;
            gl_lds16(c.Wt + (size_t)(c0+row)*c.KCpad + k0 + seg*8, &Bs[(wv*16 + j*8)*64]);
        }
        __syncthreads();
        #pragma unroll
        for (int ks = 0; ks < 64; ks += 32){
            int sw = (((ks>>3) + quad) ^ (l15 & 7)) << 3;
            short8 a0 = *(const short8*)&As[(wv*32      + l15)*64 + sw];
            short8 a1 = *(const short8*)&As[(wv*32 + 16 + l15)*64 + sw];
            short8 b0 = *(const short8*)&Bs[(     l15)*64 + sw];
            short8 b1 = *(const short8*)&Bs[(16 + l15)*64 + sw];
            short8 b2 = *(const short8*)&Bs[(32 + l15)*64 + sw];
            short8 b3 = *(const short8*)&Bs[(48 + l15)*64 + sw];
            acc[0][0] = __builtin_amdgcn_mfma_f32_16x16x32_bf16(a0,b0,acc[0][0],0,0,0);
            acc[0][1] = __builtin_amdgcn_mfma_f32_16x16x32_bf16(a0,b1,acc[0][1],0,0,0);
            acc[0][2] = __builtin_amdgcn_mfma_f32_16x16x32_bf16(a0,b2,acc[0][2],0,0,0);
            acc[0][3] = __builtin_amdgcn_mfma_f32_16x16x32_bf16(a0,b3,acc[0][3],0,0,0);
            acc[1][0] = __builtin_amdgcn_mfma_f32_16x16x32_bf16(a1,b0,acc[1][0],0,0,0);
            acc[1][1] = __builtin_amdgcn_mfma_f32_16x16x32_bf16(a1,b1,acc[1][1],0,0,0);
            acc[1][2] = __builtin_amdgcn_mfma_f32_16x16x32_bf16(a1,b2,acc[1][2],0,0,0);
            acc[1][3] = __builtin_amdgcn_mfma_f32_16x16x32_bf16(a1,b3,acc[1][3],0,0,0);
        }
        __syncthreads();
    }
    #pragma unroll
    for (int i2=0;i2<2;++i2){
        #pragma unroll
        for (int j=0;j<4;++j){
            int cc = c0 + j*16 + l15;
            #pragma unroll
            for (int r=0;r<4;++r){
                int gr = r0 + wv*32 + i2*16 + quad*4 + r;
                if (gr >= c.rows) continue;
                float v = acc[i2][j][r] + c.bias[cc];
                if (MODE == 0){
                    v = 1.f/(1.f + __expf(-v));
                    c.zr[(size_t)gr*256 + cc] = v;
                } else {
                    float hc   = tanhf(v);
                    float z    = c.zr[(size_t)gr*256 + cc];
                    float hold = c.hb[(size_t)gr*128 + cc];
                    c.hb[(size_t)gr*128 + cc] = z*hold + (1.f - z)*hc;
                }
            }
        }
    }
}

// ---------------------------------------------------------------------------
// proj: out = h1 @ Wp + bp; writes fp32 out + fp32 xdec + (optional) bf16
// x-cols of F0 slot0 (decoder feedback, layout [h|x] -> cols xoff,xoff+1).
// ---------------------------------------------------------------------------
__global__ __launch_bounds__(256) void proj(const float* __restrict__ h1,
                                            const float* __restrict__ Wp,
                                            const float* __restrict__ bp,
                                            float* __restrict__ xdec,
                                            float* __restrict__ out, int t,
                                            u16* __restrict__ F0x, int KC0, int xoff){
    int row  = blockIdx.x * 4 + (threadIdx.x >> 6);
    int lane = threadIdx.x & 63;
    float v0 = h1[(size_t)row*128 + lane];
    float v1 = h1[(size_t)row*128 + 64 + lane];
    float w00 = Wp[lane*2+0],      w01 = Wp[lane*2+1];
    float w10 = Wp[(64+lane)*2+0], w11 = Wp[(64+lane)*2+1];
    float a0 = v0*w00 + v1*w10;
    float a1 = v0*w01 + v1*w11;
    #pragma unroll
    for (int off=32; off>0; off>>=1){
        a0 += __shfl_down(a0, off);
        a1 += __shfl_down(a1, off);
    }
    if (lane == 0){
        a0 += bp[0];
        a1 += bp[1];
        xdec[(size_t)row*2+0] = a0;
        xdec[(size_t)row*2+1] = a1;
        if (F0x){
            F0x[(size_t)row*KC0 + xoff    ] = f2b(a0);
            F0x[(size_t)row*KC0 + xoff + 1] = f2b(a1);
        }
        int b = row / N_, n = row % N_;
        size_t o = ((size_t)(b*T_ + t)*N_ + n)*2;
        out[o]   = a0;
        out[o+1] = a1;
    }
}

// go_init: zero xdec and F0 slot0 x-cols
__global__ void go_init(float* __restrict__ xdec, u16* __restrict__ F0, int KC0, int xoff){
    int i = blockIdx.x*256 + threadIdx.x;
    if (i >= BN) return;
    xdec[2*i] = 0.f; xdec[2*i+1] = 0.f;
    F0[(size_t)i*KC0 + xoff] = 0; F0[(size_t)i*KC0 + xoff + 1] = 0;
}

// ---------------------------------------------------------------------------
struct Layer {
    u16 *F, *Ft; float *zr; float *h;
    const u16 *Wg, *Wc; const float *bg, *bc;
    int C, KC, KCpad, ctiles, Cpad, xoff, xdim, hoff;
};

extern "C" void kernel_launch(void* const* d_in, const int* in_sizes, int n_in,
                              void* d_out, int out_size, void* d_ws, size_t ws_size,
                              hipStream_t stream){
    float* out = (float*)d_out;

    char* pb = (char*)d_ws;
    auto alloc = [&](size_t bytes)->void*{
        void* r = (void*)pb;
        pb += (bytes + 255) & ~(size_t)255;
        return r;
    };

    int* flag = (int*)alloc(16);
    sniff<<<1, 64, 0, stream>>>(d_in[2], flag);

    const int idxs[11] = {0,4,6,8,10,12,14,16,18,19,20};
    float* cw[21] = {nullptr};
    CvtArgs ca;
    int maxn = 0;
    for (int ii = 0; ii < 11; ++ii){
        int i = idxs[ii];
        int n = in_sizes[i];
        cw[i] = (float*)alloc((size_t)n*4);
        ca.src[ii] = d_in[i];
        ca.dst[ii] = cw[i];
        ca.n[ii]   = n;
        if (n > maxn) maxn = n;
    }
    cvt_all<<<dim3((maxn+255)/256, 11), 256, 0, stream>>>(ca, flag);
    const float* src = cw[0];

    float* msq  = (float*)alloc((size_t)4*N_*N_*4);
    float* h0   = (float*)alloc((size_t)BN*H_*4);
    float* h1   = (float*)alloc((size_t)BN*H_*4);
    float* xdec = (float*)alloc((size_t)BN*DIN*4);
    u16*   asq  = (u16*)alloc((size_t)4*AROWS*DPITCH*2);

    // wt: L0 weights get row-perm 130 ([x|h]->[h|x]); L1 no perm
    const int widx[8]  = {3,5,7,9,11,13,15,17};
    const int wKC[8]   = {650,650,1280,1280,650,650,1280,1280};
    const int wNout[8] = {256,128,256,128,256,128,256,128};
    const int wPerm[8] = {130,130,0,0,130,130,0,0};
    u16* wt[8];
    for (int i=0;i<8;++i){
        int KCpad = (wKC[i] + 63) & ~63;
        wt[i] = (u16*)alloc((size_t)wNout[i]*KCpad*2);
        wtrans<<<dim3(KCpad/64, wNout[i]/64), 256, 0, stream>>>(d_in[widx[i]], wt[i], wKC[i], wNout[i], KCpad, wPerm[i], flag);
    }

    {
        dim3 g((N_+15)/16, (N_+15)/16, 2), b(16,16);
        support_prep<<<g, b, 0, stream>>>(d_in[2], flag, msq);
        int tot = 4*AROWS*DPITCH;
        asq_prep<<<dim3((tot+255)/256), 256, 0, stream>>>(msq, asq);
    }
    hipMemsetAsync(h0, 0, sizeof(float)*(size_t)BN*H_*2, stream);  // h0 and h1

    size_t fixed = (size_t)(pb - (char*)d_ws);
    size_t need0 = (size_t)BN*256*4 + (size_t)BN*650*2  + (size_t)B_*192*DPITCH*2;
    size_t need1 = (size_t)BN*256*4 + (size_t)BN*1280*2 + (size_t)B_*256*DPITCH*2;
    bool dual = (fixed + need0 + need1 + (4<<20)) <= ws_size;

    auto ceil8 = [](int x){ return ((x+7)/8)*8; };
    auto mkFill = [&](Layer& L, const float* x, long xbs, int b0, int Bc, int ftiles)->FillCfg{
        return FillCfg{L.F, L.Ft, x, L.h, xbs, L.C, L.KC, L.Cpad,
                       L.xoff, L.xdim, L.hoff, ftiles, b0, 6*ftiles*Bc};
    };
    auto mkDiff = [&](Layer& L, int Bc, int coff, int ct)->DiffCfg{
        int T = Bc*ct;
        return DiffCfg{L.F, L.Ft, L.C, L.KC, L.Cpad, coff, ct, T, 12*ceil8(T)};
    };
    auto mkG0 = [&](Layer& L, int b0, int Bc)->GemmCfg{
        int rows = Bc*N_, gy = (rows+127)/128;
        return GemmCfg{L.F, L.Wg, L.bg, L.zr, L.h + (size_t)b0*N_*H_,
                       L.KC, L.KCpad, rows, gy, 4, ceil8(gy)*4};
    };
    auto mkG1 = [&](Layer& L, int b0, int Bc)->GemmCfg{
        int rows = Bc*N_, gy = (rows+127)/128;
        return GemmCfg{L.F, L.Wc, L.bc, L.zr, L.h + (size_t)b0*N_*H_,
                       L.KC, L.KCpad, rows, gy, 2, ceil8(gy)*2};
    };
    auto mkRh = [&](Layer& L, int b0, int Bc)->RhCfg{
        int total = Bc*N_*H_;
        return RhCfg{L.F, L.Ft, L.zr, L.h, L.KC, L.Cpad, L.hoff, b0, total, (total+255)/256};
    };
    auto runCellSeq = [&](Layer& L, const float* x, long xbs, int b0, int Bc){
        FillCfg f = mkFill(L, x, xbs, b0, Bc, L.Cpad/64);
        fill_k<<<dim3(f.nb), 256, 0, stream>>>(f, f, f.nb);
        DiffCfg d1 = mkDiff(L, Bc, 0, L.ctiles);
        diffuse_k<<<dim3(d1.nb), 256, 0, stream>>>(d1, d1, d1.nb, asq);
        GemmCfg g0 = mkG0(L, b0, Bc);
        gemm_k<0><<<dim3(g0.nb), 256, 0, stream>>>(g0, g0, g0.nb);
        RhCfg r = mkRh(L, b0, Bc);
        rh_k<<<dim3(r.nb), 256, 0, stream>>>(r, r, r.nb);
        DiffCfg d2 = mkDiff(L, Bc, L.hoff, 2);
        diffuse_k<<<dim3(d2.nb), 256, 0, stream>>>(d2, d2, d2.nb, asq);
        GemmCfg g1 = mkG1(L, b0, Bc);
        gemm_k<1><<<dim3(g1.nb), 256, 0, stream>>>(g1, g1, g1.nb);
    };

    if (dual){
        float* zr0 = (float*)alloc((size_t)BN*256*4);
        u16*   F0  = (u16*)alloc((size_t)BN*650*2);
        u16*   Ft0 = (u16*)alloc((size_t)B_*192*DPITCH*2);
        float* zr1 = (float*)alloc((size_t)BN*256*4);
        u16*   F1  = (u16*)alloc((size_t)BN*1280*2);
        u16*   Ft1 = (u16*)alloc((size_t)B_*256*DPITCH*2);
        alloc(1<<19);

        // L0 layout [h|x]: hoff=0, xoff=128, xdim=2
        Layer E0{F0, Ft0, zr0, h0, wt[0], wt[1], cw[4],  cw[6],  130, 650, 704, 3, 192, 128, 2,   0};
        Layer E1{F1, Ft1, zr1, h1, wt[2], wt[3], cw[8],  cw[10], 256, 1280,1280, 4, 256, 0,   128, 128};
        Layer D0{F0, Ft0, zr0, h0, wt[4], wt[5], cw[12], cw[14], 130, 650, 704, 3, 192, 128, 2,   0};
        Layer D1{F1, Ft1, zr1, h1, wt[6], wt[7], cw[16], cw[18], 256, 1280,1280, 4, 256, 0,   128, 128};

        // ------- encoder: layer-pipelined super-steps -------
        for (int s = 0; s <= T_; ++s){
            bool has0 = (s < T_), has1 = (s >= 1);
            const float* x0 = src + (size_t)s*N_*DIN;
            FillCfg f0 = mkFill(E0, x0, (long)T_*N_*DIN, 0, B_, 3);
            FillCfg f1 = mkFill(E1, h0, (long)N_*H_,     0, B_, 4);
            if (has0 && has1) fill_k<<<dim3(f0.nb+f1.nb),256,0,stream>>>(f0, f1, f0.nb);
            else if (has0)    fill_k<<<dim3(f0.nb),256,0,stream>>>(f0, f0, f0.nb);
            else              fill_k<<<dim3(f1.nb),256,0,stream>>>(f1, f1, f1.nb);

            DiffCfg a1 = mkDiff(E0, B_, 0, 3), b1 = mkDiff(E1, B_, 0, 4);
            if (has0 && has1) diffuse_k<<<dim3(a1.nb+b1.nb),256,0,stream>>>(a1, b1, a1.nb, asq);
            else if (has0)    diffuse_k<<<dim3(a1.nb),256,0,stream>>>(a1, a1, a1.nb, asq);
            else              diffuse_k<<<dim3(b1.nb),256,0,stream>>>(b1, b1, b1.nb, asq);

            GemmCfg ga = mkG0(E0, 0, B_), gb = mkG0(E1, 0, B_);
            if (has0 && has1) gemm_k<0><<<dim3(ga.nb+gb.nb),256,0,stream>>>(ga, gb, ga.nb);
            else if (has0)    gemm_k<0><<<dim3(ga.nb),256,0,stream>>>(ga, ga, ga.nb);
            else              gemm_k<0><<<dim3(gb.nb),256,0,stream>>>(gb, gb, gb.nb);

            RhCfg ra = mkRh(E0, 0, B_), rb = mkRh(E1, 0, B_);
            if (has0 && has1) rh_k<<<dim3(ra.nb+rb.nb),256,0,stream>>>(ra, rb, ra.nb);
            else if (has0)    rh_k<<<dim3(ra.nb),256,0,stream>>>(ra, ra, ra.nb);
            else              rh_k<<<dim3(rb.nb),256,0,stream>>>(rb, rb, rb.nb);

            DiffCfg a2 = mkDiff(E0, B_, 0, 2), b2 = mkDiff(E1, B_, 128, 2);
            if (has0 && has1) diffuse_k<<<dim3(a2.nb+b2.nb),256,0,stream>>>(a2, b2, a2.nb, asq);
            else if (has0)    diffuse_k<<<dim3(a2.nb),256,0,stream>>>(a2, a2, a2.nb, asq);
            else              diffuse_k<<<dim3(b2.nb),256,0,stream>>>(b2, b2, b2.nb, asq);

            GemmCfg ha = mkG1(E0, 0, B_), hb = mkG1(E1, 0, B_);
            if (has0 && has1) gemm_k<1><<<dim3(ha.nb+hb.nb),256,0,stream>>>(ha, hb, ha.nb);
            else if (has0)    gemm_k<1><<<dim3(ha.nb),256,0,stream>>>(ha, ha, ha.nb);
            else              gemm_k<1><<<dim3(hb.nb),256,0,stream>>>(hb, hb, hb.nb);
        }

        // ------- decoder: x-column pipelined -------
        go_init<<<dim3((BN+255)/256), 256, 0, stream>>>(xdec, F0, 650, 128);
        {   // pre-loop: D0(0) h-part fill + gate diffusion of h-cols
            FillCfg fh = mkFill(D0, xdec, (long)N_*DIN, 0, B_, 2);   // tiles 0,1 = h only
            fill_k<<<dim3(fh.nb), 256, 0, stream>>>(fh, fh, fh.nb);
            DiffCfg dh = mkDiff(D0, B_, 0, 2);
            diffuse_k<<<dim3(dh.nb), 256, 0, stream>>>(dh, dh, dh.nb, asq);
        }
        for (int t = 0; t < T_; ++t){
            // x-cols of slots1-4 from xdec (synth B) — tiny
            int nbx = 12*64;
            diffx_k<<<dim3(nbx), 256, 0, stream>>>(F0, xdec, asq, 130, 650, 128);
            GemmCfg g0a = mkG0(D0, 0, B_);
            gemm_k<0><<<dim3(g0a.nb),256,0,stream>>>(g0a, g0a, g0a.nb);
            RhCfg r0c = mkRh(D0, 0, B_);
            rh_k<<<dim3(r0c.nb),256,0,stream>>>(r0c, r0c, r0c.nb);
            DiffCfg d2a = mkDiff(D0, B_, 0, 2);
            diffuse_k<<<dim3(d2a.nb),256,0,stream>>>(d2a, d2a, d2a.nb, asq);
            GemmCfg g1a = mkG1(D0, 0, B_);
            gemm_k<1><<<dim3(g1a.nb),256,0,stream>>>(g1a, g1a, g1a.nb);   // h0(t)

            // D1(t) fill [+ D0(t+1) h-fill]; D1(t) d1 [+ D0(t+1) h-d1]
            FillCfg f1c = mkFill(D1, h0, (long)N_*H_, 0, B_, 4);
            DiffCfg d1c = mkDiff(D1, B_, 0, 4);
            if (t < T_-1){
                FillCfg fh = mkFill(D0, xdec, (long)N_*DIN, 0, B_, 2);
                fill_k<<<dim3(f1c.nb+fh.nb),256,0,stream>>>(f1c, fh, f1c.nb);
                DiffCfg dh = mkDiff(D0, B_, 0, 2);
                diffuse_k<<<dim3(d1c.nb+dh.nb),256,0,stream>>>(d1c, dh, d1c.nb, asq);
            } else {
                fill_k<<<dim3(f1c.nb),256,0,stream>>>(f1c, f1c, f1c.nb);
                diffuse_k<<<dim3(d1c.nb),256,0,stream>>>(d1c, d1c, d1c.nb, asq);
            }
            GemmCfg g0b = mkG0(D1, 0, B_);
            gemm_k<0><<<dim3(g0b.nb),256,0,stream>>>(g0b, g0b, g0b.nb);
            RhCfg r1c = mkRh(D1, 0, B_);
            rh_k<<<dim3(r1c.nb),256,0,stream>>>(r1c, r1c, r1c.nb);
            DiffCfg d2b = mkDiff(D1, B_, 128, 2);
            diffuse_k<<<dim3(d2b.nb),256,0,stream>>>(d2b, d2b, d2b.nb, asq);
            GemmCfg g1b = mkG1(D1, 0, B_);
            gemm_k<1><<<dim3(g1b.nb),256,0,stream>>>(g1b, g1b, g1b.nb);   // h1(t)

            proj<<<dim3(BN/4), 256, 0, stream>>>(h1, cw[19], cw[20], xdec, out, t, F0, 650, 128);
        }
    } else {
        // ------- fallback: sequential with adaptive chunking -------
        size_t perb = (size_t)N_*1280*2 + (size_t)N_*256*4 + (size_t)256*DPITCH*2;
        int Bc = 64;
        while (Bc > 2 && fixed + (1<<20) + (size_t)Bc*perb > ws_size) Bc >>= 1;
        float* zr = (float*)alloc((size_t)Bc*N_*256*4);
        u16*   F  = (u16*)alloc((size_t)Bc*N_*1280*2);
        u16*   Ft = (u16*)alloc((size_t)Bc*256*DPITCH*2);
        alloc(1<<19);

        Layer SE0{F, Ft, zr, h0, wt[0], wt[1], cw[4],  cw[6],  130, 650, 704, 3, 192, 128, 2,   0};
        Layer SE1{F, Ft, zr, h1, wt[2], wt[3], cw[8],  cw[10], 256, 1280,1280, 4, 256, 0,   128, 128};
        Layer SD0{F, Ft, zr, h0, wt[4], wt[5], cw[12], cw[14], 130, 650, 704, 3, 192, 128, 2,   0};
        Layer SD1{F, Ft, zr, h1, wt[6], wt[7], cw[16], cw[18], 256, 1280,1280, 4, 256, 0,   128, 128};

        for (int t = 0; t < T_; ++t){
            for (int b0 = 0; b0 < B_; b0 += Bc)
                runCellSeq(SE0, src + (size_t)t*N_*DIN, (long)T_*N_*DIN, b0, Bc);
            for (int b0 = 0; b0 < B_; b0 += Bc)
                runCellSeq(SE1, h0, (long)N_*H_, b0, Bc);
        }
        hipMemsetAsync(xdec, 0, sizeof(float)*(size_t)BN*DIN, stream);
        for (int t = 0; t < T_; ++t){
            for (int b0 = 0; b0 < B_; b0 += Bc)
                runCellSeq(SD0, xdec, (long)N_*DIN, b0, Bc);
            for (int b0 = 0; b0 < B_; b0 += Bc)
                runCellSeq(SD1, h0, (long)N_*H_, b0, Bc);
            proj<<<dim3(BN/4), 256, 0, stream>>>(h1, cw[19], cw[20], xdec, out, t,
                                                 (u16*)nullptr, 650, 128);
        }
    }
}